// Round 4
// baseline (1150.558 us; speedup 1.0000x reference)
//
#include <hip/hip_runtime.h>

typedef float v2f __attribute__((ext_vector_type(2)));

#define T_LEN 2048
#define NH    10
#define OUT_T 1439
#define TFIRST 608      // first output timestep (T - TAIL)
#define NSEQ  4096

#define KSIG (-1.4426950408889634f)   // -log2(e)
#define KTAN (-2.8853900817779268f)   // -2*log2(e)

static __device__ __forceinline__ v2f fma2(v2f a, v2f b, v2f c) {
  return __builtin_elementwise_fma(a, b, c);
}
static __device__ __forceinline__ v2f splat2(float v) { v2f r; r.x = v; r.y = v; return r; }
static __device__ __forceinline__ v2f mulsp(v2f a, float s) { v2f r; r.x = a.x*s; r.y = a.y*s; return r; }

// Broadcast lane s (0..31) to all lanes within each 32-lane group.
// BitMode offset = (xor<<10)|(or<<5)|and ; src = ((i&and)|or)^xor = s
#define SWZ32(v, s) __uint_as_float(__builtin_amdgcn_ds_swizzle( \
    (int)__float_as_uint(v), ((s) << 5)))
// Swap halves (lane ^= 16) within each 32-lane group: and=0x1F, xor=0x10
#define SWAP16(v) __uint_as_float(__builtin_amdgcn_ds_swizzle( \
    (int)__float_as_uint(v), 0x401F))
// DPP row_ror:N within rows of 16 (verified R1/R2): dest[i] = src[(i-N)&15]
#define ROR_F(v, N) __uint_as_float(__builtin_amdgcn_update_dpp( \
    0, (int)__float_as_uint(v), 0x120 + (N), 0xF, 0xF, true))

// 2 sequences per wave (grp = lane>>5); 32 lanes per sequence.
// Within a sequence: half = (lane>>4)&1. half0 lane u owns gate rows (i,f) of
// hidden unit u; half1 lane u owns gate rows (g,o) and the (c,h) state.
// Lanes u=10..15 on half1 carry fc1 rows folded into the layer-1 "g" slot
// (which receives tanh) — the FC head costs ~nothing.
// 4096 seqs / 2 per wave = 2048 waves = 2 waves/SIMD: stalls of one wave are
// filled by the other; per-wave issue is halved vs the 4-seq/wave layout.
__global__ void __launch_bounds__(64, 2)
lstm_fused(const float* __restrict__ x,
           const float* __restrict__ w_ih0, const float* __restrict__ w_hh0,
           const float* __restrict__ b_ih0, const float* __restrict__ b_hh0,
           const float* __restrict__ w_ih1, const float* __restrict__ w_hh1,
           const float* __restrict__ b_ih1, const float* __restrict__ b_hh1,
           const float* __restrict__ fc1_w, const float* __restrict__ fc1_b,
           const float* __restrict__ fc2_w, const float* __restrict__ fc2_b,
           float* __restrict__ out)
{
  const int lane = threadIdx.x;        // 0..63
  const int grp  = lane >> 5;          // sequence within wave (0..1)
  const int v32  = lane & 31;          // lane within sequence
  const int half = v32 >> 4;           // 0: (i,f) lanes ; 1: (g,o)+state lanes
  const int u    = v32 & 15;           // unit slot
  const int seq  = (int)blockIdx.x * 2 + grp;

  // Per-lane weights: v2f packs this lane's two gate rows (a,b) = (i,f) or (g,o)
  v2f whh0[NH], wih1[NH], whh1[NH];
  v2f b0, b1, wx;
  b0 = b1 = wx = splat2(0.f);
#pragma unroll
  for (int j = 0; j < NH; ++j) { whh0[j] = splat2(0.f); wih1[j] = splat2(0.f); whh1[j] = splat2(0.f); }

  if (u < NH) {
    const int ra = (half*2 + 0)*NH + u;   // gate row for .x  (i or g)
    const int rb = (half*2 + 1)*NH + u;   // gate row for .y  (f or o)
    wx.x = w_ih0[ra];              wx.y = w_ih0[rb];
    b0.x = b_ih0[ra] + b_hh0[ra];  b0.y = b_ih0[rb] + b_hh0[rb];
    b1.x = b_ih1[ra] + b_hh1[ra];  b1.y = b_ih1[rb] + b_hh1[rb];
#pragma unroll
    for (int j = 0; j < NH; ++j) {
      whh0[j].x = w_hh0[ra*NH+j];  whh0[j].y = w_hh0[rb*NH+j];
      wih1[j].x = w_ih1[ra*NH+j];  wih1[j].y = w_ih1[rb*NH+j];
      whh1[j].x = w_hh1[ra*NH+j];  whh1[j].y = w_hh1[rb*NH+j];
    }
  } else if (half == 1) {
    b1.x = fc1_b[u - NH];               // fc1 in the L1 "g" slot (gets tanh)
#pragma unroll
    for (int j = 0; j < NH; ++j) whh1[j].x = fc1_w[(u - NH)*NH + j];
  }

  // Branchless activation constants: x-slot is sigmoid on half0, tanh on half1.
  const float kx = half ? KTAN : KSIG;
  const float mx = half ? 2.f : 1.f;
  const float ax = half ? -1.f : 0.f;
  const float fc2wl = (half == 1 && u >= NH) ? fc2_w[u - NH] : 0.f;
  const float fc2bl = fc2_b[0];

  const float* xp   = x + (size_t)seq * T_LEN;
  float*       outp = out + (size_t)seq * OUT_T;

  float c0 = 0.f, c1 = 0.f, h0p = 0.f, h1p = 0.f;
  float xv = xp[0];

#pragma unroll 1
  for (int t = 0; t < T_LEN; ++t) {
    const int tn = (t + 1 < T_LEN) ? (t + 1) : (T_LEN - 1);
    const float xn = xp[tn];                       // prefetch next x

    // ---- broadcast h0(t-1), h1(t-1) from half1 state lanes (16+j) ----
    const float p0 = SWZ32(h0p,16), p1 = SWZ32(h0p,17), p2 = SWZ32(h0p,18),
                p3 = SWZ32(h0p,19), p4 = SWZ32(h0p,20), p5 = SWZ32(h0p,21),
                p6 = SWZ32(h0p,22), p7 = SWZ32(h0p,23), p8 = SWZ32(h0p,24),
                p9 = SWZ32(h0p,25);
    const float q0 = SWZ32(h1p,16), q1 = SWZ32(h1p,17), q2 = SWZ32(h1p,18),
                q3 = SWZ32(h1p,19), q4 = SWZ32(h1p,20), q5 = SWZ32(h1p,21),
                q6 = SWZ32(h1p,22), q7 = SWZ32(h1p,23), q8 = SWZ32(h1p,24),
                q9 = SWZ32(h1p,25);

    // ---- layer 0 gate pair (dual accumulators) ----
    v2f aA = fma2(wx, splat2(xv), b0);
    v2f aB = mulsp(whh0[1], p1);
#define L0T(j, hv, AC) AC = fma2(whh0[j], splat2(hv), AC);
    L0T(0,p0,aA) L0T(2,p2,aA) L0T(3,p3,aB) L0T(4,p4,aA) L0T(5,p5,aB)
    L0T(6,p6,aA) L0T(7,p7,aB) L0T(8,p8,aA) L0T(9,p9,aB)
#undef L0T

    // ---- layer 1 h1-recurrent part (+fc1) — independent of layer-0 acts ----
    v2f cA = fma2(whh1[0], splat2(q0), b1);
    v2f cB = mulsp(whh1[1], q1);
#define L1R(j, hv, AC) AC = fma2(whh1[j], splat2(hv), AC);
    L1R(2,q2,cA) L1R(3,q3,cB) L1R(4,q4,cA) L1R(5,q5,cB)
    L1R(6,q6,cA) L1R(7,q7,cB) L1R(8,q8,cA) L1R(9,q9,cB)
#undef L1R

    // ---- layer 0 activations ----
    const v2f g0 = aA + aB;
    const float sx0 = __builtin_fmaf(
        __builtin_amdgcn_rcpf(1.0f + __builtin_amdgcn_exp2f(g0.x * kx)), mx, ax);
    const float sy0 = __builtin_amdgcn_rcpf(1.0f + __builtin_amdgcn_exp2f(g0.y * KSIG));
    const float wx0 = SWAP16(sx0);                 // half1 receives si
    const float wy0 = SWAP16(sy0);                 // half1 receives sf
    c0 = wy0 * c0 + wx0 * sx0;                     // half1: sf*c0 + si*tg (half0: bounded garbage)
    const float tc0 = __builtin_amdgcn_rcpf(1.0f + __builtin_amdgcn_exp2f(c0 * KTAN)) * 2.f - 1.f;
    const float h0n = sy0 * tc0;                   // half1: so*tanh(c0)

    // ---- broadcast h0(t), finish layer 1 gates ----
    const float r0 = SWZ32(h0n,16), r1 = SWZ32(h0n,17), r2 = SWZ32(h0n,18),
                r3 = SWZ32(h0n,19), r4 = SWZ32(h0n,20), r5 = SWZ32(h0n,21),
                r6 = SWZ32(h0n,22), r7 = SWZ32(h0n,23), r8 = SWZ32(h0n,24),
                r9 = SWZ32(h0n,25);
#define L1I(j, hv, AC) AC = fma2(wih1[j], splat2(hv), AC);
    L1I(0,r0,cA) L1I(1,r1,cB) L1I(2,r2,cA) L1I(3,r3,cB) L1I(4,r4,cA)
    L1I(5,r5,cB) L1I(6,r6,cA) L1I(7,r7,cB) L1I(8,r8,cA) L1I(9,r9,cB)
#undef L1I

    // ---- layer 1 activations ----
    const v2f g1 = cA + cB;
    const float sx1 = __builtin_fmaf(
        __builtin_amdgcn_rcpf(1.0f + __builtin_amdgcn_exp2f(g1.x * kx)), mx, ax);
    const float sy1 = __builtin_amdgcn_rcpf(1.0f + __builtin_amdgcn_exp2f(g1.y * KSIG));
    const float wx1 = SWAP16(sx1);
    const float wy1 = SWAP16(sy1);
    c1 = wy1 * c1 + wx1 * sx1;
    const float tc1 = __builtin_amdgcn_rcpf(1.0f + __builtin_amdgcn_exp2f(c1 * KTAN)) * 2.f - 1.f;
    const float h1n = sy1 * tc1;

    // ---- fc2: output for timestep t-1 (DPP ror reduce over the half1 row) ----
    if (t > TFIRST) {                              // t in [609,2047] -> out idx 0..1438
      float y = sx1 * fc2wl;                       // nonzero only on half1 pad lanes
      y += ROR_F(y, 8);
      y += ROR_F(y, 4);
      y += ROR_F(y, 2);
      y += ROR_F(y, 1);                            // whole 16-row holds the sum
      if (v32 == 16) outp[t - 1 - TFIRST] = y + fc2bl;
    }

    h0p = h0n; h1p = h1n;
    xv = xn;
  }
}

extern "C" void kernel_launch(void* const* d_in, const int* in_sizes, int n_in,
                              void* d_out, int out_size, void* d_ws, size_t ws_size,
                              hipStream_t stream) {
  const float* x     = (const float*)d_in[0];
  const float* w_ih0 = (const float*)d_in[1];
  const float* w_hh0 = (const float*)d_in[2];
  const float* b_ih0 = (const float*)d_in[3];
  const float* b_hh0 = (const float*)d_in[4];
  const float* w_ih1 = (const float*)d_in[5];
  const float* w_hh1 = (const float*)d_in[6];
  const float* b_ih1 = (const float*)d_in[7];
  const float* b_hh1 = (const float*)d_in[8];
  const float* fc1_w = (const float*)d_in[9];
  const float* fc1_b = (const float*)d_in[10];
  const float* fc2_w = (const float*)d_in[11];
  const float* fc2_b = (const float*)d_in[12];
  float* out = (float*)d_out;

  lstm_fused<<<dim3(NSEQ / 2), dim3(64), 0, stream>>>(
      x, w_ih0, w_hh0, b_ih0, b_hh0, w_ih1, w_hh1, b_ih1, b_hh1,
      fc1_w, fc1_b, fc2_w, fc2_b, out);
}

// Round 5
// 770.780 us; speedup vs baseline: 1.4927x; 1.4927x over previous
//
#include <hip/hip_runtime.h>

typedef float v2f __attribute__((ext_vector_type(2)));

#define T_LEN 2048
#define NH    10
#define OUT_T 1439
#define TFIRST 608      // first output timestep (T - TAIL)
#define NSEQ  4096

static __device__ __forceinline__ v2f fma2(v2f a, v2f b, v2f c) {
  return __builtin_elementwise_fma(a, b, c);
}
static __device__ __forceinline__ v2f splat2(float v) { v2f r; r.x = v; r.y = v; return r; }
static __device__ __forceinline__ v2f mulsp(v2f a, float s) { v2f r; r.x = a.x*s; r.y = a.y*s; return r; }

// sigmoid(z) = rcp(1 + exp2(z * -log2(e)))
static __device__ __forceinline__ float fast_sigmoid(float z) {
  float e = __builtin_amdgcn_exp2f(z * -1.4426950408889634f);
  return __builtin_amdgcn_rcpf(1.0f + e);
}
// tanh(z) = 2*sigmoid(2z) - 1 ; overflow -> Inf -> rcp -> 0 -> -1 (saturates)
static __device__ __forceinline__ float fast_tanh(float z) {
  float e = __builtin_amdgcn_exp2f(z * -2.8853900817779268f);
  return __builtin_amdgcn_rcpf(1.0f + e) * 2.0f - 1.0f;
}

// Broadcast lane (16-group base + j) to all lanes of its 16-group (verified R2):
// BitMode src = ((i & 0x10) | j) within each 32-half.
#define SWZB(v, j) __uint_as_float(__builtin_amdgcn_ds_swizzle( \
    (int)__float_as_uint(v), (((j) << 5) | 0x10)))

// DPP row_ror:N within rows of 16 (verified R1-R3): dest[i] = src[(i-N)&15]
#define ROR_F(v, N) __uint_as_float(__builtin_amdgcn_update_dpp( \
    0, (int)__float_as_uint(v), 0x120 + (N), 0xF, 0xF, true))

// 4 sequences per wave; 16 lanes per sequence; lane u<10 owns hidden unit u
// (all four gates, packed (i,f)/(g,o) in v2f). Lanes u=10..15 carry fc1 rows
// folded into the layer-1 "g" slot (which receives tanh) — FC head is free.
//
// SOFTWARE-PIPELINED SCHEDULE (the R4 change): iteration n computes
//   L1 gates/acts for t=n   (consumes r = bcast h0(n), q = bcast h1(n-1))
//   L0 gates/acts for t=n+1 (consumes the SAME r)
//   one broadcast batch: q' = h1(n), r' = h0(n+1)   [issued at tail]
//   fc2 + loop overhead fill the broadcast latency shadow.
// -> one (mostly hidden) cross-lane segment per step instead of two serial
//    ones, and 20 instead of 30 swizzles per wave-step.
__global__ void __launch_bounds__(64, 1)
lstm_fused(const float* __restrict__ x,
           const float* __restrict__ w_ih0, const float* __restrict__ w_hh0,
           const float* __restrict__ b_ih0, const float* __restrict__ b_hh0,
           const float* __restrict__ w_ih1, const float* __restrict__ w_hh1,
           const float* __restrict__ b_ih1, const float* __restrict__ b_hh1,
           const float* __restrict__ fc1_w, const float* __restrict__ fc1_b,
           const float* __restrict__ fc2_w, const float* __restrict__ fc2_b,
           float* __restrict__ out)
{
  const int lane = threadIdx.x;       // 0..63
  const int grp  = lane >> 4;         // sequence within wave (0..3) == 16-group
  const int u    = lane & 15;         // unit slot within group
  const int seq  = (int)blockIdx.x * 4 + grp;

  v2f whh0_if[NH], whh0_go[NH], wih1_if[NH], wih1_go[NH], whh1_if[NH], whh1_go[NH];
  v2f b0_if, b0_go, b1_if, b1_go, wx_if, wx_go;
  b0_if = b0_go = b1_if = b1_go = wx_if = wx_go = splat2(0.f);
#pragma unroll
  for (int j = 0; j < NH; ++j) {
    whh0_if[j] = splat2(0.f); whh0_go[j] = splat2(0.f);
    wih1_if[j] = splat2(0.f); wih1_go[j] = splat2(0.f);
    whh1_if[j] = splat2(0.f); whh1_go[j] = splat2(0.f);
  }

  if (u < NH) {
    const int ri = 0*NH+u, rf = 1*NH+u, rg = 2*NH+u, ro = 3*NH+u;
    wx_if.x = w_ih0[ri]; wx_if.y = w_ih0[rf];
    wx_go.x = w_ih0[rg]; wx_go.y = w_ih0[ro];
    b0_if.x = b_ih0[ri] + b_hh0[ri]; b0_if.y = b_ih0[rf] + b_hh0[rf];
    b0_go.x = b_ih0[rg] + b_hh0[rg]; b0_go.y = b_ih0[ro] + b_hh0[ro];
    b1_if.x = b_ih1[ri] + b_hh1[ri]; b1_if.y = b_ih1[rf] + b_hh1[rf];
    b1_go.x = b_ih1[rg] + b_hh1[rg]; b1_go.y = b_ih1[ro] + b_hh1[ro];
#pragma unroll
    for (int j = 0; j < NH; ++j) {
      whh0_if[j].x = w_hh0[ri*NH+j]; whh0_if[j].y = w_hh0[rf*NH+j];
      whh0_go[j].x = w_hh0[rg*NH+j]; whh0_go[j].y = w_hh0[ro*NH+j];
      wih1_if[j].x = w_ih1[ri*NH+j]; wih1_if[j].y = w_ih1[rf*NH+j];
      wih1_go[j].x = w_ih1[rg*NH+j]; wih1_go[j].y = w_ih1[ro*NH+j];
      whh1_if[j].x = w_hh1[ri*NH+j]; whh1_if[j].y = w_hh1[rf*NH+j];
      whh1_go[j].x = w_hh1[rg*NH+j]; whh1_go[j].y = w_hh1[ro*NH+j];
    }
  } else {
    b1_go.x = fc1_b[u - NH];          // fc1 bias in the L1 "g" slot (gets tanh)
#pragma unroll
    for (int j = 0; j < NH; ++j) whh1_go[j].x = fc1_w[(u - NH)*NH + j];
  }

  const float fc2wl = (u >= NH) ? fc2_w[u - NH] : 0.f;
  const float fc2bl = fc2_b[0];

  const float* xp   = x + (size_t)seq * T_LEN;
  float*       outp = out + (size_t)seq * OUT_T;

  // ---- prologue: layer 0 at t=0 (h0(-1)=0, c0(-1)=0) ----
  float c0, c1 = 0.f;
  float r0,r1,r2,r3,r4,r5,r6,r7,r8,r9;       // bcast of h0(n)   (current)
  float q0,q1,q2,q3,q4,q5,q6,q7,q8,q9;       // bcast of h1(n-1)
  {
    const float x0 = xp[0];
    const v2f g0if = fma2(wx_if, splat2(x0), b0_if);
    const v2f g0go = fma2(wx_go, splat2(x0), b0_go);
    const float si = fast_sigmoid(g0if.x);
    const float tg = fast_tanh(g0go.x);
    const float so = fast_sigmoid(g0go.y);
    c0 = si * tg;
    const float h0 = so * fast_tanh(c0);
    r0 = SWZB(h0,0); r1 = SWZB(h0,1); r2 = SWZB(h0,2); r3 = SWZB(h0,3);
    r4 = SWZB(h0,4); r5 = SWZB(h0,5); r6 = SWZB(h0,6); r7 = SWZB(h0,7);
    r8 = SWZB(h0,8); r9 = SWZB(h0,9);
    q0=q1=q2=q3=q4=q5=q6=q7=q8=q9 = 0.f;
  }

#pragma unroll 1
  for (int n = 0; n < T_LEN; ++n) {
    const int tn = (n + 1 < T_LEN) ? (n + 1) : (T_LEN - 1);
    const float xn = xp[tn];                       // x(n+1), issued early

    // ---- L1 gates (t=n): 4 accumulators, 5-deep chains ----
    v2f cA = fma2(wih1_if[0], splat2(r0), b1_if);
    v2f hA = fma2(wih1_go[0], splat2(r0), b1_go);
    v2f cB = mulsp(wih1_if[1], r1);
    v2f hB = mulsp(wih1_go[1], r1);
    v2f cC = mulsp(whh1_if[0], q0);
    v2f hC = mulsp(whh1_go[0], q0);
    v2f cD = mulsp(whh1_if[1], q1);
    v2f hD = mulsp(whh1_go[1], q1);
#define L1I(j, hv, AC, GC) { const v2f s = splat2(hv); \
    AC = fma2(wih1_if[j], s, AC); GC = fma2(wih1_go[j], s, GC); }
#define L1R(j, hv, AC, GC) { const v2f s = splat2(hv); \
    AC = fma2(whh1_if[j], s, AC); GC = fma2(whh1_go[j], s, GC); }
    L1I(2,r2,cA,hA) L1I(3,r3,cB,hB) L1I(4,r4,cA,hA) L1I(5,r5,cB,hB)
    L1I(6,r6,cA,hA) L1I(7,r7,cB,hB) L1I(8,r8,cA,hA) L1I(9,r9,cB,hB)
    L1R(2,q2,cC,hC) L1R(3,q3,cD,hD) L1R(4,q4,cC,hC) L1R(5,q5,cD,hD)
    L1R(6,q6,cC,hC) L1R(7,q7,cD,hD) L1R(8,q8,cC,hC) L1R(9,q9,cD,hD)
#undef L1I
#undef L1R

    // ---- L0 gates (t=n+1): same r broadcast, dual accumulators ----
    v2f aA = fma2(wx_if, splat2(xn), b0_if);
    v2f gA = fma2(wx_go, splat2(xn), b0_go);
    v2f aB = mulsp(whh0_if[1], r1);
    v2f gB = mulsp(whh0_go[1], r1);
#define L0T(j, hv, AC, GC) { const v2f s = splat2(hv); \
    AC = fma2(whh0_if[j], s, AC); GC = fma2(whh0_go[j], s, GC); }
    L0T(0,r0,aA,gA) L0T(2,r2,aA,gA) L0T(3,r3,aB,gB) L0T(4,r4,aA,gA)
    L0T(5,r5,aB,gB) L0T(6,r6,aA,gA) L0T(7,r7,aB,gB) L0T(8,r8,aA,gA)
    L0T(9,r9,aB,gB)
#undef L0T

    // ---- L1 activations -> h1(n) ----
    const v2f g1if = (cA + cB) + (cC + cD);
    const v2f g1go = (hA + hB) + (hC + hD);
    const float si1 = fast_sigmoid(g1if.x);
    const float sf1 = fast_sigmoid(g1if.y);
    const float tg1 = fast_tanh(g1go.x);           // fc lanes: tanh(fc1(h1(n-1)))
    const float so1 = fast_sigmoid(g1go.y);
    c1 = sf1 * c1 + si1 * tg1;
    const float h1n = so1 * fast_tanh(c1);

    // ---- L0 activations -> h0(n+1)  (independent chain, overlaps L1's) ----
    const v2f g0if = aA + aB;
    const v2f g0go = gA + gB;
    const float si0 = fast_sigmoid(g0if.x);
    const float sf0 = fast_sigmoid(g0if.y);
    const float tg0 = fast_tanh(g0go.x);
    const float so0 = fast_sigmoid(g0go.y);
    c0 = sf0 * c0 + si0 * tg0;
    const float h0n = so0 * fast_tanh(c0);

    // ---- single broadcast batch for next iteration (issued at tail) ----
    q0 = SWZB(h1n,0); q1 = SWZB(h1n,1); q2 = SWZB(h1n,2); q3 = SWZB(h1n,3);
    q4 = SWZB(h1n,4); q5 = SWZB(h1n,5); q6 = SWZB(h1n,6); q7 = SWZB(h1n,7);
    q8 = SWZB(h1n,8); q9 = SWZB(h1n,9);
    r0 = SWZB(h0n,0); r1 = SWZB(h0n,1); r2 = SWZB(h0n,2); r3 = SWZB(h0n,3);
    r4 = SWZB(h0n,4); r5 = SWZB(h0n,5); r6 = SWZB(h0n,6); r7 = SWZB(h0n,7);
    r8 = SWZB(h0n,8); r9 = SWZB(h0n,9);

    // ---- fc2 (independent of broadcasts — fills their latency shadow) ----
    if (n > TFIRST) {                              // n in [609,2047] -> out idx 0..1438
      float y = tg1 * fc2wl;                       // zero on lanes u<10
      y += ROR_F(y, 8);
      y += ROR_F(y, 4);
      y += ROR_F(y, 2);
      y += ROR_F(y, 1);                            // all 16 lanes hold row sum
      if (u == 0) outp[n - 1 - TFIRST] = y + fc2bl;
    }
  }
}

extern "C" void kernel_launch(void* const* d_in, const int* in_sizes, int n_in,
                              void* d_out, int out_size, void* d_ws, size_t ws_size,
                              hipStream_t stream) {
  const float* x     = (const float*)d_in[0];
  const float* w_ih0 = (const float*)d_in[1];
  const float* w_hh0 = (const float*)d_in[2];
  const float* b_ih0 = (const float*)d_in[3];
  const float* b_hh0 = (const float*)d_in[4];
  const float* w_ih1 = (const float*)d_in[5];
  const float* w_hh1 = (const float*)d_in[6];
  const float* b_ih1 = (const float*)d_in[7];
  const float* b_hh1 = (const float*)d_in[8];
  const float* fc1_w = (const float*)d_in[9];
  const float* fc1_b = (const float*)d_in[10];
  const float* fc2_w = (const float*)d_in[11];
  const float* fc2_b = (const float*)d_in[12];
  float* out = (float*)d_out;

  lstm_fused<<<dim3(NSEQ / 4), dim3(64), 0, stream>>>(
      x, w_ih0, w_hh0, b_ih0, b_hh0, w_ih1, w_hh1, b_ih1, b_hh1,
      fc1_w, fc1_b, fc2_w, fc2_b, out);
}